// Round 10
// baseline (238.420 us; speedup 1.0000x reference)
//
#include <hip/hip_runtime.h>
#include <hip/hip_bf16.h>
#include <cstdint>
#include <cstddef>

typedef __attribute__((ext_vector_type(8))) short short8;
typedef __attribute__((ext_vector_type(4))) float f32x4;

static constexpr int M_TOT = 31744;
static constexpr int N_TOT = 1152;
static constexpr int K_TOT = 768;
static constexpr long A_ELEMS = (long)M_TOT * K_TOT;   // 24379392
static constexpr long W_ELEMS = (long)N_TOT * K_TOT;   // 884736
static constexpr int CYC_ROWS = 3968;                  // one ragged cycle (4 images)

__device__ __forceinline__ unsigned short f2bf(float f) {
  unsigned int u = __float_as_uint(f);
  u += 0x7FFFu + ((u >> 16) & 1u);   // round-to-nearest-even
  return (unsigned short)(u >> 16);
}
__device__ __forceinline__ float bf2f(unsigned short u) {
  return __uint_as_float((unsigned int)u << 16);
}

// ---------------- pass 1: fp32 -> bf16 for A (seq_patches) and W ----------------
__global__ void cvt_kernel(const float* __restrict__ A, const float* __restrict__ W,
                           unsigned short* __restrict__ dst) {
  long chunk = (long)blockIdx.x * blockDim.x + threadIdx.x;  // one chunk = 8 floats
  long i = chunk * 8;
  const float* src = (i < A_ELEMS) ? (A + i) : (W + (i - A_ELEMS));
  float4 v0 = *(const float4*)(src);
  float4 v1 = *(const float4*)(src + 4);
  short8 o;
  o[0] = (short)f2bf(v0.x); o[1] = (short)f2bf(v0.y);
  o[2] = (short)f2bf(v0.z); o[3] = (short)f2bf(v0.w);
  o[4] = (short)f2bf(v1.x); o[5] = (short)f2bf(v1.y);
  o[6] = (short)f2bf(v1.z); o[7] = (short)f2bf(v1.w);
  *(short8*)(dst + i) = o;
}

// ---------------- pass 1b: pos table  tab[rem,d] = bf16(bias[d] + bilinear(pos)[rem,d]) ----
__global__ void tab_kernel(const float* __restrict__ pos, const float* __restrict__ bias,
                           unsigned short* __restrict__ tab) {
  const int t = blockIdx.x * blockDim.x + threadIdx.x;   // 571392 = 3968 * 144
  const int row = t / 144;                                // rem in [0,3968)
  const int dc = (t - row * 144) * 8;                     // d chunk base

  int rr, cc; float sy, sx;
  if (row < 1024)      { rr = row >> 5; cc = row & 31; sy = 0.5f;         sx = 0.5f; }
  else if (row < 2048) { const int li = row - 1024; rr = li >> 6; cc = li & 63; sy = 1.0f; sx = 0.25f; }
  else if (row < 3008) { const int li = row - 2048; rr = li / 40; cc = li - rr * 40; sy = 16.0f / 24.0f; sx = 0.4f; }
  else                 { const int li = row - 3008; rr = li / 24; cc = li - rr * 24; sy = 0.4f; sx = 16.0f / 24.0f; }
  float yc = fminf(fmaxf(((float)rr + 0.5f) * sy - 0.5f, 0.0f), 15.0f);
  const int y0 = (int)yc; const float fy = yc - (float)y0;
  const int y1 = y0 < 15 ? y0 + 1 : 15;
  float xc = fminf(fmaxf(((float)cc + 0.5f) * sx - 0.5f, 0.0f), 15.0f);
  const int x0 = (int)xc; const float fx = xc - (float)x0;
  const int x1 = x0 < 15 ? x0 + 1 : 15;
  const float w11 = fy * fx;
  const float w10 = fy - w11;
  const float w01 = fx - w11;
  const float w00 = 1.0f - fy - fx + w11;
  const float* p00 = pos + (size_t)(y0 * 16 + x0) * 1152 + dc;
  const float* p01 = pos + (size_t)(y0 * 16 + x1) * 1152 + dc;
  const float* p10 = pos + (size_t)(y1 * 16 + x0) * 1152 + dc;
  const float* p11 = pos + (size_t)(y1 * 16 + x1) * 1152 + dc;
  const float* bi  = bias + dc;
  short8 o;
#pragma unroll
  for (int j = 0; j < 8; ++j) {
    const float v = bi[j] + w00 * p00[j] + w01 * p01[j] + w10 * p10[j] + w11 * p11[j];
    o[j] = (short)f2bf(v);
  }
  *(short8*)(tab + (size_t)row * 1152 + dc) = o;
}

// ---------------- pass 2: LDS-FREE bf16 MFMA GEMM (pure TLP latency hiding) ----
// 128x128 tile, 256 threads = 4 waves (2x2), wave-tile 64x64, 12 K-tiles.
// NO __shared__, NO barriers: MFMA A/B fragments load DIRECTLY from row-major
// global (each wave-load = 16 rows x 64 B segments; W and A-panels L2-resident,
// XCD swizzle keeps the A panel in one XCD's L2). Latency hidden by occupancy:
// launch_bounds(256,3) -> ~12 waves/CU of fully independent waves.
__global__ __launch_bounds__(256, 3) void gemm_kernel(
    const unsigned short* __restrict__ Abf, const unsigned short* __restrict__ Wbf,
    const unsigned short* __restrict__ tab, float* __restrict__ outp) {
  // XCD-bijective swizzle: 2232 tiles = 8 XCDs * 279.
  const int bid = blockIdx.x;
  const int tile = (bid & 7) * 279 + (bid >> 3);
  const int tm = tile / 9, tn = tile % 9;   // 248 x 9 tiles of 128x128
  const int m0 = tm * 128, n0 = tn * 128;

  const int tid = threadIdx.x;
  const int wid = tid >> 6, lane = tid & 63;
  const int wr = wid >> 1, wc = wid & 1;    // 2x2 waves, 64x64 each
  const int kg = lane >> 4, l15 = lane & 15;

  // Per-lane fragment base pointers (MFMA layout direct from global):
  // A row = m0 + wr*64 + m*16 + l15, k-octet = kg*8 (+32 for kk=1, +128B/Ktile imm)
  const unsigned short* Ab[4];
  const unsigned short* Bb[4];
#pragma unroll
  for (int m = 0; m < 4; ++m)
    Ab[m] = Abf + (size_t)(m0 + wr * 64 + m * 16 + l15) * K_TOT + kg * 8;
#pragma unroll
  for (int n = 0; n < 4; ++n)
    Bb[n] = Wbf + (size_t)(n0 + wc * 64 + n * 16 + l15) * K_TOT + kg * 8;

  f32x4 acc[4][4] = {};

#pragma unroll
  for (int t = 0; t < 12; ++t) {
    const int ko = t * 64;   // element offset of this K-tile (imm-foldable)
    short8 fa0[4], fb0[4], fa1[4], fb1[4];
#pragma unroll
    for (int n = 0; n < 4; ++n) fb0[n] = *(const short8*)(Bb[n] + ko);
#pragma unroll
    for (int m = 0; m < 4; ++m) fa0[m] = *(const short8*)(Ab[m] + ko);
#pragma unroll
    for (int n = 0; n < 4; ++n) fb1[n] = *(const short8*)(Bb[n] + ko + 32);
#pragma unroll
    for (int m = 0; m < 4; ++m) fa1[m] = *(const short8*)(Ab[m] + ko + 32);
    __builtin_amdgcn_s_setprio(1);
#pragma unroll
    for (int m = 0; m < 4; ++m)
#pragma unroll
      for (int n = 0; n < 4; ++n)
        acc[m][n] = __builtin_amdgcn_mfma_f32_16x16x32_bf16(fa0[m], fb0[n], acc[m][n], 0, 0, 0);
#pragma unroll
    for (int m = 0; m < 4; ++m)
#pragma unroll
      for (int n = 0; n < 4; ++n)
        acc[m][n] = __builtin_amdgcn_mfma_f32_16x16x32_bf16(fa1[m], fb1[n], acc[m][n], 0, 0, 0);
    __builtin_amdgcn_s_setprio(0);
  }

  // ---------------- epilogue (r5-verified): out = acc + tab[s % 3968, d] ----------
  const int s_base = m0 + wr * 64 + ((lane >> 4) << 2);  // + m*16 + r
  const int rem_base = s_base % CYC_ROWS;
  const int d_base = n0 + wc * 64 + l15;                 // + n*16

#pragma unroll
  for (int m = 0; m < 4; ++m) {
#pragma unroll
    for (int r = 0; r < 4; ++r) {
      const int off = m * 16 + r;
      int rem = rem_base + off;
      if (rem >= CYC_ROWS) rem -= CYC_ROWS;
      const unsigned short* trow = tab + (size_t)rem * 1152 + d_base;
      float* orow = outp + (size_t)(s_base + off) * 1152 + d_base;
#pragma unroll
      for (int n = 0; n < 4; ++n)
        orow[n * 16] = acc[m][n][r] + bf2f(trow[n * 16]);
    }
  }
}

extern "C" void kernel_launch(void* const* d_in, const int* in_sizes, int n_in,
                              void* d_out, int out_size, void* d_ws, size_t ws_size,
                              hipStream_t stream) {
  const float* A    = (const float*)d_in[0];  // seq_patches [31744,768]
  const float* W    = (const float*)d_in[1];  // w [1152,768]
  const float* bias = (const float*)d_in[2];  // b [1152]
  const float* pos  = (const float*)d_in[3];  // pos_emb [256,1152]
  unsigned short* Abf = (unsigned short*)d_ws;            // 48.76 MB
  unsigned short* Wbf = Abf + A_ELEMS;                    // +1.77 MB
  unsigned short* tab = Wbf + W_ELEMS;                    // +9.14 MB (3968*1152)
  float* outp = (float*)d_out;

  cvt_kernel<<<12336, 256, 0, stream>>>(A, W, Abf);
  tab_kernel<<<2232, 256, 0, stream>>>(pos, bias, tab);
  gemm_kernel<<<2232, 256, 0, stream>>>(Abf, Wbf, tab, outp);
}

// Round 11
// 129.177 us; speedup vs baseline: 1.8457x; 1.8457x over previous
//
#include <hip/hip_runtime.h>
#include <hip/hip_bf16.h>
#include <cstdint>
#include <cstddef>

typedef __attribute__((ext_vector_type(8))) short short8;
typedef __attribute__((ext_vector_type(4))) float f32x4;

static constexpr int M_TOT = 31744;
static constexpr int N_TOT = 1152;
static constexpr int K_TOT = 768;
static constexpr long W_ELEMS = (long)N_TOT * K_TOT;   // 884736
static constexpr int CYC_ROWS = 3968;                  // one ragged cycle (4 images)

__device__ __forceinline__ unsigned short f2bf(float f) {
  unsigned int u = __float_as_uint(f);
  u += 0x7FFFu + ((u >> 16) & 1u);   // round-to-nearest-even
  return (unsigned short)(u >> 16);
}
__device__ __forceinline__ float bf2f(unsigned short u) {
  return __uint_as_float((unsigned int)u << 16);
}
__device__ __forceinline__ unsigned int cvtpk(float lo, float hi) {
  unsigned int r;
  asm("v_cvt_pk_bf16_f32 %0, %1, %2" : "=v"(r) : "v"(lo), "v"(hi));
  return r;
}

// ---------------- prep: W fp32->bf16 (blocks 0..431) + pos table (blocks 432..2663) ----
__global__ void prep_kernel(const float* __restrict__ W, const float* __restrict__ pos,
                            const float* __restrict__ bias,
                            unsigned short* __restrict__ Wbf, unsigned short* __restrict__ tab) {
  const int b = blockIdx.x;
  if (b < 432) {   // 432*256*8 = 884736 = W_ELEMS exactly
    const long i = ((long)b * 256 + threadIdx.x) * 8;
    float4 v0 = *(const float4*)(W + i);
    float4 v1 = *(const float4*)(W + i + 4);
    short8 o;
    o[0] = (short)f2bf(v0.x); o[1] = (short)f2bf(v0.y);
    o[2] = (short)f2bf(v0.z); o[3] = (short)f2bf(v0.w);
    o[4] = (short)f2bf(v1.x); o[5] = (short)f2bf(v1.y);
    o[6] = (short)f2bf(v1.z); o[7] = (short)f2bf(v1.w);
    *(short8*)(Wbf + i) = o;
    return;
  }
  const int t = (b - 432) * 256 + threadIdx.x;   // 571392 = 3968 * 144
  const int row = t / 144;
  const int dc = (t - row * 144) * 8;

  int rr, cc; float sy, sx;
  if (row < 1024)      { rr = row >> 5; cc = row & 31; sy = 0.5f;         sx = 0.5f; }
  else if (row < 2048) { const int li = row - 1024; rr = li >> 6; cc = li & 63; sy = 1.0f; sx = 0.25f; }
  else if (row < 3008) { const int li = row - 2048; rr = li / 40; cc = li - rr * 40; sy = 16.0f / 24.0f; sx = 0.4f; }
  else                 { const int li = row - 3008; rr = li / 24; cc = li - rr * 24; sy = 0.4f; sx = 16.0f / 24.0f; }
  float yc = fminf(fmaxf(((float)rr + 0.5f) * sy - 0.5f, 0.0f), 15.0f);
  const int y0 = (int)yc; const float fy = yc - (float)y0;
  const int y1 = y0 < 15 ? y0 + 1 : 15;
  float xc = fminf(fmaxf(((float)cc + 0.5f) * sx - 0.5f, 0.0f), 15.0f);
  const int x0 = (int)xc; const float fx = xc - (float)x0;
  const int x1 = x0 < 15 ? x0 + 1 : 15;
  const float w11 = fy * fx;
  const float w10 = fy - w11;
  const float w01 = fx - w11;
  const float w00 = 1.0f - fy - fx + w11;
  const float* p00 = pos + (size_t)(y0 * 16 + x0) * 1152 + dc;
  const float* p01 = pos + (size_t)(y0 * 16 + x1) * 1152 + dc;
  const float* p10 = pos + (size_t)(y1 * 16 + x0) * 1152 + dc;
  const float* p11 = pos + (size_t)(y1 * 16 + x1) * 1152 + dc;
  const float* bi  = bias + dc;
  short8 o;
#pragma unroll
  for (int j = 0; j < 8; ++j) {
    const float v = bi[j] + w00 * p00[j] + w01 * p01[j] + w10 * p10[j] + w11 * p11[j];
    o[j] = (short)f2bf(v);
  }
  *(short8*)(tab + (size_t)row * 1152 + dc) = o;
}

__device__ __forceinline__ void gload_lds16(const void* g, void* l) {
  __builtin_amdgcn_global_load_lds((__attribute__((address_space(1))) void*)g,
                                   (__attribute__((address_space(3))) void*)l, 16, 0, 0);
}

// ---------------- GEMM (r7 structure) with fused A fp32->bf16 reg-staging ----------
// 128x128 tile, BK=32, 24 K-steps, 256 threads = 4 waves (2x2), wave-tile 64x64.
// LDS 3 x (A 8KB + B 8KB) = 48 KB, 2-ahead B prefetch via gload_lds (r7 ledger).
// A: 4 float4 fp32 loads -> regs (issued FIRST each iter), cvt_pk + swizzled
// ds_write after COMPUTE. Counted waits never cover loads younger than 1 tile:
//   wait1 vmcnt(8) = A(t+1)4 + B(t+1)2 + B(t+2)2 outstanding -> B(t) resident
//   wait2 vmcnt(4) = B(t+1)+B(t+2) outstanding -> A(t+1) regs ready
__global__ __launch_bounds__(256, 3) void gemm_kernel(
    const float* __restrict__ Afp, const unsigned short* __restrict__ Wbf,
    const unsigned short* __restrict__ tab, float* __restrict__ outp) {
  __shared__ __attribute__((aligned(16))) unsigned short As[3][128 * 32];  // 3 x 8 KB
  __shared__ __attribute__((aligned(16))) unsigned short Bs[3][128 * 32];  // 3 x 8 KB

  // XCD-bijective swizzle: 2232 tiles = 8 XCDs * 279.
  const int bid = blockIdx.x;
  const int tile = (bid & 7) * 279 + (bid >> 3);
  const int tm = tile / 9, tn = tile % 9;   // 248 x 9 tiles of 128x128
  const int m0 = tm * 128, n0 = tn * 128;

  const int tid = threadIdx.x;
  const int wid = tid >> 6, lane = tid & 63;
  const int wr = wid >> 1, wc = wid & 1;    // 2x2 waves, 64x64 each
  const int kg = lane >> 4, l15 = lane & 15;
  const int rb = wid * 32;                  // A-staging row base (32 rows/wave)

  // A reg-staging map: row = rb + (lane>>1), k-half = (lane&1)*16 fp32 (64 B/lane)
  const int arow_s = rb + (lane >> 1);
  const float* Afp0 = Afp + (size_t)(m0 + arow_s) * K_TOT + (lane & 1) * 16;
  // ds_write chunks c = (lane&1)*2 + j, XOR key = (row>>1)&3 = (lane>>2)&3
  const int wkey = (lane >> 2) & 3;
  char* const awbase = (char*)nullptr;  // (unused; kept for clarity)

  // B staging (r7 verbatim): rows n0 + wid*16 + srow and +64
  const int srow = lane >> 2;
  const int schunk = ((lane & 3) ^ ((lane >> 3) & 3)) * 8;
  const unsigned short* Bbase = Wbf + (size_t)(n0 + wid * 16 + srow) * K_TOT + schunk;
  const int wu = wid << 10;                 // wave-uniform LDS byte base

  const int rkey = (l15 >> 1) & 3;          // ds_read swizzle key (r7)

  f32x4 acc[4][4] = {};
  float4 fA[4];                             // in-flight A fp32 (held across COMPUTE)

#define ALOAD(kt)                                                                \
  { const float* s_ = Afp0 + (kt) * 32;                                          \
    fA[0] = *(const float4*)(s_);                                                \
    fA[1] = *(const float4*)(s_ + 4);                                            \
    fA[2] = *(const float4*)(s_ + 8);                                            \
    fA[3] = *(const float4*)(s_ + 12); }

#define AWRITE(p_)                                                               \
  { int4 w01, w23;                                                               \
    w01.x = (int)cvtpk(fA[0].x, fA[0].y); w01.y = (int)cvtpk(fA[0].z, fA[0].w);  \
    w01.z = (int)cvtpk(fA[1].x, fA[1].y); w01.w = (int)cvtpk(fA[1].z, fA[1].w);  \
    w23.x = (int)cvtpk(fA[2].x, fA[2].y); w23.y = (int)cvtpk(fA[2].z, fA[2].w);  \
    w23.z = (int)cvtpk(fA[3].x, fA[3].y); w23.w = (int)cvtpk(fA[3].z, fA[3].w);  \
    char* b_ = (char*)As[p_] + arow_s * 64;                                      \
    const int c0_ = (lane & 1) * 2;                                              \
    *(int4*)(b_ + ((c0_ ^ wkey) << 4)) = w01;                                    \
    *(int4*)(b_ + (((c0_ + 1) ^ wkey) << 4)) = w23; }

#define STAGE_B(p_, kt)                                                          \
  { const int k0_ = (kt) * 32;                                                   \
    gload_lds16(Bbase + k0_,                      (char*)Bs[p_] + wu);           \
    gload_lds16(Bbase + (size_t)64 * K_TOT + k0_, (char*)Bs[p_] + 4096 + wu); }

#define COMPUTE(p_)                                                              \
  { __builtin_amdgcn_s_setprio(1);                                               \
    short8 fa[4], fb[4];                                                         \
    _Pragma("unroll") for (int m = 0; m < 4; ++m) {                              \
      const int ar_ = wr * 64 + m * 16 + l15;                                    \
      fa[m] = *(const short8*)((const char*)As[p_] + ar_ * 64 +                  \
                               ((kg ^ rkey) << 4));                              \
    }                                                                            \
    _Pragma("unroll") for (int n = 0; n < 4; ++n) {                              \
      const int br_ = wc * 64 + n * 16 + l15;                                    \
      fb[n] = *(const short8*)((const char*)Bs[p_] + br_ * 64 +                  \
                               ((kg ^ rkey) << 4));                              \
    }                                                                            \
    _Pragma("unroll") for (int m = 0; m < 4; ++m)                                \
      _Pragma("unroll") for (int n = 0; n < 4; ++n)                              \
        acc[m][n] = __builtin_amdgcn_mfma_f32_16x16x32_bf16(                     \
            fa[m], fb[n], acc[m][n], 0, 0, 0);                                   \
    __builtin_amdgcn_s_setprio(0); }

  // prologue: A(0) via regs (full drain once), B(0),B(1) in flight
  ALOAD(0)
  STAGE_B(0, 0)
  STAGE_B(1, 1)
  asm volatile("s_waitcnt vmcnt(4)" ::: "memory");   // A(0) done; B0,B1 flying
  AWRITE(0)

#pragma unroll
  for (int t = 0; t < 24; ++t) {
    const int p = t % 3;
    if (t < 23) ALOAD(t + 1)                         // A first (older than B!)
    if (t < 22) STAGE_B((t + 2) % 3, t + 2)
    if (t < 22)      { asm volatile("s_waitcnt vmcnt(8)" ::: "memory"); }
    else if (t == 22){ asm volatile("s_waitcnt vmcnt(6)" ::: "memory"); }
    else             { asm volatile("s_waitcnt vmcnt(0)" ::: "memory"); }
    __syncthreads();                                 // As[p],Bs[p] resident+visible
    COMPUTE(p)
    if (t < 23) {
      if (t < 22) { asm volatile("s_waitcnt vmcnt(4)" ::: "memory"); }
      else        { asm volatile("s_waitcnt vmcnt(2)" ::: "memory"); }
      AWRITE((t + 1) % 3)                            // cvt + swizzled ds_write
      __syncthreads();                               // protect bufs being read
    }
  }

#undef ALOAD
#undef AWRITE
#undef STAGE_B
#undef COMPUTE

  // ---------------- epilogue (r5/r7-verified): out = acc + tab[s % 3968, d] -------
  const int s_base = m0 + wr * 64 + ((lane >> 4) << 2);
  const int rem_base = s_base % CYC_ROWS;
  const int d_base = n0 + wc * 64 + l15;

#pragma unroll
  for (int m = 0; m < 4; ++m) {
#pragma unroll
    for (int r = 0; r < 4; ++r) {
      const int off = m * 16 + r;
      int rem = rem_base + off;
      if (rem >= CYC_ROWS) rem -= CYC_ROWS;
      const unsigned short* trow = tab + (size_t)rem * 1152 + d_base;
      float* orow = outp + (size_t)(s_base + off) * 1152 + d_base;
#pragma unroll
      for (int n = 0; n < 4; ++n)
        orow[n * 16] = acc[m][n][r] + bf2f(trow[n * 16]);
    }
  }
}

extern "C" void kernel_launch(void* const* d_in, const int* in_sizes, int n_in,
                              void* d_out, int out_size, void* d_ws, size_t ws_size,
                              hipStream_t stream) {
  const float* A    = (const float*)d_in[0];  // seq_patches [31744,768] fp32
  const float* W    = (const float*)d_in[1];  // w [1152,768] fp32
  const float* bias = (const float*)d_in[2];  // b [1152]
  const float* pos  = (const float*)d_in[3];  // pos_emb [256,1152]
  unsigned short* Wbf = (unsigned short*)d_ws;            // 1.77 MB
  unsigned short* tab = Wbf + W_ELEMS;                    // +9.14 MB
  float* outp = (float*)d_out;

  prep_kernel<<<2664, 256, 0, stream>>>(W, pos, bias, Wbf, tab);
  gemm_kernel<<<2232, 256, 0, stream>>>(A, Wbf, tab, outp);
}